// Round 1
// baseline (367.920 us; speedup 1.0000x reference)
//
// T5 encoder layer — bf16 MFMA pipeline, round 1 (correctness-first baseline)
// Pipeline: cvt(x) / cvtT(weights) / bias-table -> QKV gemms -> flash attn
//           -> Wo gemm -> LN1 -> FFN1(relu) -> FFN2 -> LN2 -> d_out
#include <hip/hip_runtime.h>

typedef __bf16 bf16_t;
typedef __bf16 bf16x8 __attribute__((ext_vector_type(8)));
typedef __bf16 bf16x4 __attribute__((ext_vector_type(4)));
typedef float  f32x4  __attribute__((ext_vector_type(4)));

#define MFMA_BF16 __builtin_amdgcn_mfma_f32_16x16x32_bf16

__device__ __forceinline__ void gload_lds16(const void* g, void* l) {
  __builtin_amdgcn_global_load_lds((const __attribute__((address_space(1))) void*)g,
                                   (__attribute__((address_space(3))) void*)l,
                                   16, 0, 0);
}

// ---------------- f32 -> bf16 flat convert (float4 per thread) ----------------
__global__ __launch_bounds__(256) void cvt_k(const float* __restrict__ s,
                                             bf16_t* __restrict__ d, int n4) {
  int i = blockIdx.x * 256 + threadIdx.x;
  if (i >= n4) return;
  float4 v = ((const float4*)s)[i];
  bf16x4 o = { (bf16_t)v.x, (bf16_t)v.y, (bf16_t)v.z, (bf16_t)v.w };
  ((bf16x4*)d)[i] = o;
}

// ---------------- f32 [K][N] -> bf16 [N][K] transpose-convert ----------------
__global__ __launch_bounds__(256) void cvtT_k(const float* __restrict__ src,
                                              bf16_t* __restrict__ dst,
                                              int K, int N) {
  __shared__ float t[64][65];
  int n0 = blockIdx.x * 64, k0 = blockIdx.y * 64;
  int tx = threadIdx.x & 63, g = threadIdx.x >> 6;
#pragma unroll
  for (int i = g; i < 64; i += 4) t[i][tx] = src[(size_t)(k0 + i) * N + n0 + tx];
  __syncthreads();
#pragma unroll
  for (int i = g; i < 64; i += 4)
    dst[(size_t)(n0 + i) * K + k0 + tx] = (bf16_t)t[tx][i];
}

// ---------------- T5 relative position bias table: bt[h][(q-k)+2047] ----------------
__global__ __launch_bounds__(256) void relbias_k(const float* __restrict__ rb,
                                                 float* __restrict__ bt) {
  int i = blockIdx.x * 256 + threadIdx.x;
  if (i >= 8 * 4095) return;
  int h = i / 4095;
  int r = (i % 4095) - 2047;          // rel = q - k
  int ret = (r < 0) ? 16 : 0;
  int n = (r < 0) ? -r : r;
  int b;
  if (n < 8) b = n;
  else {
    float v = logf((float)n / 8.0f) / logf(16.0f) * 8.0f;  // matches ref f32 math
    int vi = 8 + (int)v;
    b = vi < 15 ? vi : 15;
  }
  bt[i] = rb[h * 32 + ret + b];
}

// ---------------- bf16 MFMA GEMM: C[M][N] = A[M][K] @ Bt[N][K]^T + bias ----------------
// 128x128 tile, BK=64, 256 threads (4 waves 2x2), 16x16x32 MFMA, global_load_lds staging.
template <int OUT_F32, int RELU>
__global__ __launch_bounds__(256) void gemm_k(const bf16_t* __restrict__ A,
                                              const bf16_t* __restrict__ Bt,
                                              const float* __restrict__ bias,
                                              void* __restrict__ outp,
                                              int M, int N, int K) {
  __shared__ __align__(16) bf16_t As[128 * 64];
  __shared__ __align__(16) bf16_t Bs[128 * 64];
  const int tid = threadIdx.x;
  const int lane = tid & 63, wid = tid >> 6;
  const int m0 = blockIdx.x * 128, n0 = blockIdx.y * 128;
  const int wr = wid >> 1, wc = wid & 1;
  const int l15 = lane & 15, lg = lane >> 4;

  f32x4 acc[4][4];
#pragma unroll
  for (int i = 0; i < 4; i++)
#pragma unroll
    for (int j = 0; j < 4; j++) acc[i][j] = f32x4{0.f, 0.f, 0.f, 0.f};

  const int srow = lane >> 3;          // 0..7 row within 8-row stage chunk
  const int scol = (lane & 7) * 8;     // 16B column chunk
  const bf16_t* Ag = A + (size_t)(m0 + wid * 32 + srow) * K + scol;
  const bf16_t* Bg = Bt + (size_t)(n0 + wid * 32 + srow) * K + scol;
  bf16_t* Al = As + wid * 32 * 64;
  bf16_t* Bl = Bs + wid * 32 * 64;

  for (int k0 = 0; k0 < K; k0 += 64) {
    __syncthreads();                    // previous compute done before overwrite
#pragma unroll
    for (int i = 0; i < 4; i++) {       // each wave stages 32 rows of A and Bt
      gload_lds16(Ag + (size_t)i * 8 * K + k0, Al + i * 8 * 64);
      gload_lds16(Bg + (size_t)i * 8 * K + k0, Bl + i * 8 * 64);
    }
    asm volatile("s_waitcnt vmcnt(0)" ::: "memory");
    __syncthreads();
#pragma unroll
    for (int ks = 0; ks < 2; ks++) {
      bf16x8 af[4], bf[4];
#pragma unroll
      for (int i = 0; i < 4; i++)
        af[i] = *(const bf16x8*)(As + (wr * 64 + i * 16 + l15) * 64 + ks * 32 + lg * 8);
#pragma unroll
      for (int j = 0; j < 4; j++)
        bf[j] = *(const bf16x8*)(Bs + (wc * 64 + j * 16 + l15) * 64 + ks * 32 + lg * 8);
#pragma unroll
      for (int i = 0; i < 4; i++)
#pragma unroll
        for (int j = 0; j < 4; j++)
          acc[i][j] = MFMA_BF16(af[i], bf[j], acc[i][j], 0, 0, 0);
    }
  }

  // epilogue: C/D layout col=lane&15, row=(lane>>4)*4+reg
  const int r0 = m0 + wr * 64 + (lg << 2);
  const int c0 = n0 + wc * 64 + l15;
#pragma unroll
  for (int j = 0; j < 4; j++) {
    const int col = c0 + j * 16;
    const float bv = bias[col];
#pragma unroll
    for (int i = 0; i < 4; i++) {
      const int row = r0 + i * 16;
#pragma unroll
      for (int r = 0; r < 4; r++) {
        float v = acc[i][j][r] + bv;
        if (RELU) v = fmaxf(v, 0.f);
        if (OUT_F32) ((float*)outp)[(size_t)(row + r) * N + col] = v;
        else         ((bf16_t*)outp)[(size_t)(row + r) * N + col] = (bf16_t)v;
      }
    }
  }
}

// ---------------- flash attention with T5 bias ----------------
// grid (S/64, B*H); 4 waves, each owns 16 q rows; KV tiles of 64.
__global__ __launch_bounds__(256) void attn_k(const bf16_t* __restrict__ Q,
                                              const bf16_t* __restrict__ Kp,
                                              const bf16_t* __restrict__ Vp,
                                              const float* __restrict__ btab,
                                              bf16_t* __restrict__ ctx) {
  __shared__ __align__(16) bf16_t Ks[64 * 64];
  __shared__ __align__(16) bf16_t Vt[64 * 64];   // transposed: Vt[d][kv]
  __shared__ __align__(16) bf16_t Ps[4][16 * 64];
  const int tid = threadIdx.x;
  const int lane = tid & 63, wid = tid >> 6;
  const int q0 = blockIdx.x * 64;
  const int bb = blockIdx.y >> 3, h = blockIdx.y & 7;
  const size_t rbase = (size_t)bb * 2048 * 512;
  const int hc = h * 64;
  const int l15 = lane & 15, lg = lane >> 4;

  // Q fragments (A-frag: row=lane&15, k=(lane>>4)*8+j)
  const bf16_t* qp = Q + rbase + (size_t)(q0 + wid * 16 + l15) * 512 + hc + lg * 8;
  bf16x8 qf0 = *(const bf16x8*)qp;
  bf16x8 qf1 = *(const bf16x8*)(qp + 32);

  float mrow[4], lrow[4];
  f32x4 acc[4];
#pragma unroll
  for (int j = 0; j < 4; j++) { mrow[j] = -3.0e38f; lrow[j] = 0.f; acc[j] = f32x4{0.f, 0.f, 0.f, 0.f}; }

  const float* bt = btab + (size_t)h * 4095 + 2047;          // index by (q-k)
  const float SCL = 0.125f * 1.44269504088896f;              // (1/sqrt(64))*log2(e)

  for (int kv0 = 0; kv0 < 2048; kv0 += 64) {
    __syncthreads();
    // stage K tile (this wave: rows wid*16..+15), linear [kv][d]
#pragma unroll
    for (int i = 0; i < 2; i++) {
      int r0 = wid * 16 + i * 8;
      const bf16_t* src = Kp + rbase + (size_t)(kv0 + r0 + (lane >> 3)) * 512 + hc + (lane & 7) * 8;
      gload_lds16(src, Ks + r0 * 64);
    }
    // stage V transposed (reg-staged scalar LDS writes)
    {
      int r = tid >> 2;
      int c0 = (tid & 3) * 16;
      const bf16_t* vs = Vp + rbase + (size_t)(kv0 + r) * 512 + hc + c0;
      bf16x8 v0 = *(const bf16x8*)vs;
      bf16x8 v1 = *(const bf16x8*)(vs + 8);
#pragma unroll
      for (int j = 0; j < 8; j++) Vt[(c0 + j) * 64 + r] = v0[j];
#pragma unroll
      for (int j = 0; j < 8; j++) Vt[(c0 + 8 + j) * 64 + r] = v1[j];
    }
    asm volatile("s_waitcnt vmcnt(0)" ::: "memory");
    __syncthreads();

    // QK^T: s[n] is 16q x 16kv fragment, n over 64 kv cols
    f32x4 s[4];
#pragma unroll
    for (int n = 0; n < 4; n++) s[n] = f32x4{0.f, 0.f, 0.f, 0.f};
#pragma unroll
    for (int ks = 0; ks < 2; ks++) {
      bf16x8 qf = ks ? qf1 : qf0;
#pragma unroll
      for (int n = 0; n < 4; n++) {
        bf16x8 kf = *(const bf16x8*)(Ks + (n * 16 + l15) * 64 + ks * 32 + lg * 8);
        s[n] = MFMA_BF16(qf, kf, s[n], 0, 0, 0);
      }
    }

    // logits in base-2 domain: l2 = (qk + bias) * (1/8)*log2e
    const int rq = q0 + wid * 16 + (lg << 2);   // q row of reg 0
    const int ck = kv0 + l15;
    float lg2[4][4], mnew[4];
#pragma unroll
    for (int j = 0; j < 4; j++) mnew[j] = mrow[j];
#pragma unroll
    for (int n = 0; n < 4; n++) {
      const float* btn = bt + (rq - (ck + n * 16));   // +j gives bias[(rq+j)-kcol]
#pragma unroll
      for (int j = 0; j < 4; j++)
        lg2[n][j] = (s[n][j] + btn[j]) * SCL;
    }
#pragma unroll
    for (int j = 0; j < 4; j++) {
      float mx = fmaxf(fmaxf(lg2[0][j], lg2[1][j]), fmaxf(lg2[2][j], lg2[3][j]));
      mnew[j] = fmaxf(mnew[j], mx);
    }
#pragma unroll
    for (int off = 1; off < 16; off <<= 1)
#pragma unroll
      for (int j = 0; j < 4; j++)
        mnew[j] = fmaxf(mnew[j], __shfl_xor(mnew[j], off, 64));

    float resc[4], psum[4];
#pragma unroll
    for (int j = 0; j < 4; j++) {
      resc[j] = exp2f(mrow[j] - mnew[j]);
      mrow[j] = mnew[j];
      psum[j] = 0.f;
    }
#pragma unroll
    for (int n = 0; n < 4; n++)
#pragma unroll
      for (int j = 0; j < 4; j++) {
        float p = exp2f(lg2[n][j] - mrow[j]);
        psum[j] += p;
        Ps[wid][((lg << 2) + j) * 64 + n * 16 + l15] = (bf16_t)p;
      }
#pragma unroll
    for (int off = 1; off < 16; off <<= 1)
#pragma unroll
      for (int j = 0; j < 4; j++) psum[j] += __shfl_xor(psum[j], off, 64);
#pragma unroll
    for (int j = 0; j < 4; j++) lrow[j] = lrow[j] * resc[j] + psum[j];
#pragma unroll
    for (int dn = 0; dn < 4; dn++) {
      f32x4 t = acc[dn];
      t[0] *= resc[0]; t[1] *= resc[1]; t[2] *= resc[2]; t[3] *= resc[3];
      acc[dn] = t;
    }
    asm volatile("s_waitcnt lgkmcnt(0)" ::: "memory");
    // PV: A-frag = P (rows q, k=kv), B-frag = V from Vt[d][kv]
#pragma unroll
    for (int ks = 0; ks < 2; ks++) {
      bf16x8 pa = *(const bf16x8*)(&Ps[wid][l15 * 64 + ks * 32 + lg * 8]);
#pragma unroll
      for (int dn = 0; dn < 4; dn++) {
        bf16x8 vf = *(const bf16x8*)(Vt + (dn * 16 + l15) * 64 + ks * 32 + lg * 8);
        acc[dn] = MFMA_BF16(pa, vf, acc[dn], 0, 0, 0);
      }
    }
  }

  const int qr0 = q0 + wid * 16 + (lg << 2);
  float inv[4] = {1.f / lrow[0], 1.f / lrow[1], 1.f / lrow[2], 1.f / lrow[3]};
#pragma unroll
  for (int dn = 0; dn < 4; dn++)
#pragma unroll
    for (int j = 0; j < 4; j++)
      ctx[rbase + (size_t)(qr0 + j) * 512 + hc + dn * 16 + l15] = (bf16_t)(acc[dn][j] * inv[j]);
}

// ---------------- residual + LayerNorm (one wave per row of 512) ----------------
__global__ __launch_bounds__(256) void lnres_k(const float* __restrict__ a,
                                               const float* __restrict__ bsrc,
                                               const float* __restrict__ sc,
                                               const float* __restrict__ bi,
                                               float* __restrict__ outf,
                                               bf16_t* __restrict__ outb) {
  int row = blockIdx.x * 4 + (threadIdx.x >> 6);
  int lane = threadIdx.x & 63;
  size_t base = (size_t)row * 512 + lane * 8;
  float4 a0 = *(const float4*)(a + base), a1 = *(const float4*)(a + base + 4);
  float4 b0 = *(const float4*)(bsrc + base), b1 = *(const float4*)(bsrc + base + 4);
  float v[8] = {a0.x + b0.x, a0.y + b0.y, a0.z + b0.z, a0.w + b0.w,
                a1.x + b1.x, a1.y + b1.y, a1.z + b1.z, a1.w + b1.w};
  float s1 = 0.f, s2 = 0.f;
#pragma unroll
  for (int j = 0; j < 8; j++) { s1 += v[j]; s2 += v[j] * v[j]; }
#pragma unroll
  for (int off = 1; off < 64; off <<= 1) {
    s1 += __shfl_xor(s1, off, 64);
    s2 += __shfl_xor(s2, off, 64);
  }
  float mu = s1 * (1.f / 512.f);
  float var = s2 * (1.f / 512.f) - mu * mu;
  float rstd = rsqrtf(var + 1e-6f);
  int c = lane * 8;
  float4 sc0 = *(const float4*)(sc + c), sc1 = *(const float4*)(sc + c + 4);
  float4 bi0 = *(const float4*)(bi + c), bi1 = *(const float4*)(bi + c + 4);
  float scv[8] = {sc0.x, sc0.y, sc0.z, sc0.w, sc1.x, sc1.y, sc1.z, sc1.w};
  float biv[8] = {bi0.x, bi0.y, bi0.z, bi0.w, bi1.x, bi1.y, bi1.z, bi1.w};
  float o[8];
#pragma unroll
  for (int j = 0; j < 8; j++) o[j] = (v[j] - mu) * rstd * scv[j] + biv[j];
  *(float4*)(outf + base) = make_float4(o[0], o[1], o[2], o[3]);
  *(float4*)(outf + base + 4) = make_float4(o[4], o[5], o[6], o[7]);
  if (outb) {
    bf16x8 ob = {(bf16_t)o[0], (bf16_t)o[1], (bf16_t)o[2], (bf16_t)o[3],
                 (bf16_t)o[4], (bf16_t)o[5], (bf16_t)o[6], (bf16_t)o[7]};
    *(bf16x8*)(outb + base) = ob;
  }
}

// ---------------- host launcher ----------------
extern "C" void kernel_launch(void* const* d_in, const int* in_sizes, int n_in,
                              void* d_out, int out_size, void* d_ws, size_t ws_size,
                              hipStream_t stream) {
  const float* x    = (const float*)d_in[0];
  const float* Wq   = (const float*)d_in[1];
  const float* bq   = (const float*)d_in[2];
  const float* Wk   = (const float*)d_in[3];
  const float* bk   = (const float*)d_in[4];
  const float* Wv   = (const float*)d_in[5];
  const float* bv   = (const float*)d_in[6];
  const float* Wo   = (const float*)d_in[7];
  const float* bo   = (const float*)d_in[8];
  const float* relb = (const float*)d_in[9];
  const float* W1   = (const float*)d_in[10];
  const float* b1   = (const float*)d_in[11];
  const float* W2   = (const float*)d_in[12];
  const float* b2   = (const float*)d_in[13];
  const float* ln1s = (const float*)d_in[14];
  const float* ln1b = (const float*)d_in[15];
  const float* ln2s = (const float*)d_in[16];
  const float* ln2b = (const float*)d_in[17];

  char* w = (char*)d_ws;
  bf16_t* xb   = (bf16_t*)(w + 0);          //  8 MB  [8192][512]
  bf16_t* qb   = (bf16_t*)(w + 8388608);    //  8 MB
  bf16_t* kb   = (bf16_t*)(w + 16777216);   //  8 MB
  bf16_t* vb   = (bf16_t*)(w + 25165824);   //  8 MB
  bf16_t* ctxb = (bf16_t*)(w + 33554432);   //  8 MB
  bf16_t* x1b  = (bf16_t*)(w + 41943040);   //  8 MB
  bf16_t* WqT  = (bf16_t*)(w + 50331648);   // 512 KB [512][512]
  bf16_t* WkT  = (bf16_t*)(w + 50855936);
  bf16_t* WvT  = (bf16_t*)(w + 51380224);
  bf16_t* WoT  = (bf16_t*)(w + 51904512);
  bf16_t* W1T  = (bf16_t*)(w + 52428800);   //  2 MB [2048][512]
  bf16_t* W2T  = (bf16_t*)(w + 54525952);   //  2 MB [512][2048]
  float*  btab = (float*)(w + 56623104);    // 128 KB [8][4095]
  float*  x1f  = (float*)(w + 56754176);    // 16 MB
  float*  tmpf = (float*)(w + 73531392);    // 16 MB (Wo out, then FFN2 out)
  bf16_t* ffh  = (bf16_t*)(w + 0);          // 32 MB [8192][2048], reuses xb..vb

  // conversions + bias table
  cvt_k<<<4096, 256, 0, stream>>>(x, xb, 8192 * 512 / 4);
  cvtT_k<<<dim3(8, 8), 256, 0, stream>>>(Wq, WqT, 512, 512);
  cvtT_k<<<dim3(8, 8), 256, 0, stream>>>(Wk, WkT, 512, 512);
  cvtT_k<<<dim3(8, 8), 256, 0, stream>>>(Wv, WvT, 512, 512);
  cvtT_k<<<dim3(8, 8), 256, 0, stream>>>(Wo, WoT, 512, 512);
  cvtT_k<<<dim3(32, 8), 256, 0, stream>>>(W1, W1T, 512, 2048);
  cvtT_k<<<dim3(8, 32), 256, 0, stream>>>(W2, W2T, 2048, 512);
  relbias_k<<<128, 256, 0, stream>>>(relb, btab);

  // QKV projections
  gemm_k<0, 0><<<dim3(64, 4), 256, 0, stream>>>(xb, WqT, bq, qb, 8192, 512, 512);
  gemm_k<0, 0><<<dim3(64, 4), 256, 0, stream>>>(xb, WkT, bk, kb, 8192, 512, 512);
  gemm_k<0, 0><<<dim3(64, 4), 256, 0, stream>>>(xb, WvT, bv, vb, 8192, 512, 512);

  // attention
  attn_k<<<dim3(32, 32), 256, 0, stream>>>(qb, kb, vb, btab, ctxb);

  // Wo + residual LN1
  gemm_k<1, 0><<<dim3(64, 4), 256, 0, stream>>>(ctxb, WoT, bo, tmpf, 8192, 512, 512);
  lnres_k<<<2048, 256, 0, stream>>>(x, tmpf, ln1s, ln1b, x1f, x1b);

  // FFN
  gemm_k<0, 1><<<dim3(64, 16), 256, 0, stream>>>(x1b, W1T, b1, ffh, 8192, 2048, 512);
  gemm_k<1, 0><<<dim3(64, 4), 256, 0, stream>>>(ffh, W2T, b2, tmpf, 8192, 512, 2048);
  lnres_k<<<2048, 256, 0, stream>>>(x1f, tmpf, ln2s, ln2b, (float*)d_out, (bf16_t*)nullptr);
}

// Round 2
// 305.832 us; speedup vs baseline: 1.2030x; 1.2030x over previous
//
// T5 encoder layer — round 2: T2 XOR-swizzle (attn + gemm), fused QKV,
// far-tile constant bias, 64x128 tiles for N=512 GEMMs.
#include <hip/hip_runtime.h>

typedef __bf16 bf16_t;
typedef __bf16 bf16x8 __attribute__((ext_vector_type(8)));
typedef __bf16 bf16x4 __attribute__((ext_vector_type(4)));
typedef float  f32x4  __attribute__((ext_vector_type(4)));

#define MFMA_BF16 __builtin_amdgcn_mfma_f32_16x16x32_bf16

__device__ __forceinline__ void gload_lds16(const void* g, void* l) {
  __builtin_amdgcn_global_load_lds((const __attribute__((address_space(1))) void*)g,
                                   (__attribute__((address_space(3))) void*)l,
                                   16, 0, 0);
}

// swizzled fragment read from a [rows][64-bf16] LDS tile (128B rows).
// byte = (row*128 + c2) ^ ((row&7)<<4); c2 = byte col offset (multiple of 16).
__device__ __forceinline__ bf16x8 lds_frag(const bf16_t* base, int row, int c2) {
  return *(const bf16x8*)((const char*)base + ((((row) << 7) + c2) ^ ((row & 7) << 4)));
}

// ---------------- f32 -> bf16 flat convert ----------------
__global__ __launch_bounds__(256) void cvt_k(const float* __restrict__ s,
                                             bf16_t* __restrict__ d, int n4) {
  int i = blockIdx.x * 256 + threadIdx.x;
  if (i >= n4) return;
  float4 v = ((const float4*)s)[i];
  bf16x4 o = { (bf16_t)v.x, (bf16_t)v.y, (bf16_t)v.z, (bf16_t)v.w };
  ((bf16x4*)d)[i] = o;
}

// ---------------- f32 [K][N] -> bf16 [N][K] transpose-convert ----------------
__global__ __launch_bounds__(256) void cvtT_k(const float* __restrict__ src,
                                              bf16_t* __restrict__ dst,
                                              int K, int N) {
  __shared__ float t[64][65];
  int n0 = blockIdx.x * 64, k0 = blockIdx.y * 64;
  int tx = threadIdx.x & 63, g = threadIdx.x >> 6;
#pragma unroll
  for (int i = g; i < 64; i += 4) t[i][tx] = src[(size_t)(k0 + i) * N + n0 + tx];
  __syncthreads();
#pragma unroll
  for (int i = g; i < 64; i += 4)
    dst[(size_t)(n0 + i) * K + k0 + tx] = (bf16_t)t[tx][i];
}

// ---------------- T5 bias table bt[h][(q-k)+2047] ----------------
__global__ __launch_bounds__(256) void relbias_k(const float* __restrict__ rb,
                                                 float* __restrict__ bt) {
  int i = blockIdx.x * 256 + threadIdx.x;
  if (i >= 8 * 4095) return;
  int h = i / 4095;
  int r = (i % 4095) - 2047;
  int ret = (r < 0) ? 16 : 0;
  int n = (r < 0) ? -r : r;
  int b;
  if (n < 8) b = n;
  else {
    float v = logf((float)n / 8.0f) / logf(16.0f) * 8.0f;
    int vi = 8 + (int)v;
    b = vi < 15 ? vi : 15;
  }
  bt[i] = rb[h * 32 + ret + b];
}

// ---------------- concat 3x512 f32 ----------------
__global__ __launch_bounds__(256) void cat3_k(const float* __restrict__ a,
                                              const float* __restrict__ b,
                                              const float* __restrict__ c,
                                              float* __restrict__ o) {
  int i = blockIdx.x * 256 + threadIdx.x;
  if (i >= 1536) return;
  o[i] = (i < 512) ? a[i] : (i < 1024) ? b[i - 512] : c[i - 1024];
}

// ---------------- bf16 MFMA GEMM with T2 swizzle ----------------
// C[M][N] = A[M][K] @ Bt[N][K]^T + bias.  BMxBN tile, BK=64, 4 waves (WRxWC).
template <int BM, int BN, int WR, int WC, int OUT_F32, int RELU>
__global__ __launch_bounds__(256) void gemm_k(const bf16_t* __restrict__ A,
                                              const bf16_t* __restrict__ Bt,
                                              const float* __restrict__ bias,
                                              void* __restrict__ outp,
                                              int M, int N, int K) {
  constexpr int AI = BM / WR / 16;
  constexpr int BJ = BN / WC / 16;
  __shared__ __align__(16) bf16_t As[BM * 64];
  __shared__ __align__(16) bf16_t Bs[BN * 64];
  const int tid = threadIdx.x;
  const int lane = tid & 63, wid = tid >> 6;
  const int m0 = blockIdx.x * BM, n0 = blockIdx.y * BN;
  const int wr = wid / WC, wc = wid % WC;
  const int l15 = lane & 15, lg = lane >> 4;
  const int srow = lane >> 3;
  const int scolx = ((lane & 7) ^ srow) * 8;   // pre-swizzled source column

  f32x4 acc[AI][BJ];
#pragma unroll
  for (int i = 0; i < AI; i++)
#pragma unroll
    for (int j = 0; j < BJ; j++) acc[i][j] = f32x4{0.f, 0.f, 0.f, 0.f};

  const bf16_t* Ag = A + (size_t)(m0 + wid * (BM / 4) + srow) * K + scolx;
  const bf16_t* Bg = Bt + (size_t)(n0 + wid * (BN / 4) + srow) * K + scolx;
  bf16_t* Al = As + wid * (BM / 4) * 64;
  bf16_t* Bl = Bs + wid * (BN / 4) * 64;

  for (int k0 = 0; k0 < K; k0 += 64) {
    __syncthreads();
#pragma unroll
    for (int i = 0; i < BM / 32; i++)
      gload_lds16(Ag + (size_t)i * 8 * K + k0, Al + i * 8 * 64);
#pragma unroll
    for (int i = 0; i < BN / 32; i++)
      gload_lds16(Bg + (size_t)i * 8 * K + k0, Bl + i * 8 * 64);
    asm volatile("s_waitcnt vmcnt(0)" ::: "memory");
    __syncthreads();
#pragma unroll
    for (int ks = 0; ks < 2; ks++) {
      const int c2 = ks * 64 + lg * 16;
      bf16x8 af[AI], bfv[BJ];
#pragma unroll
      for (int i = 0; i < AI; i++)
        af[i] = lds_frag(As, wr * (BM / WR) + i * 16 + l15, c2);
#pragma unroll
      for (int j = 0; j < BJ; j++)
        bfv[j] = lds_frag(Bs, wc * (BN / WC) + j * 16 + l15, c2);
#pragma unroll
      for (int i = 0; i < AI; i++)
#pragma unroll
        for (int j = 0; j < BJ; j++)
          acc[i][j] = MFMA_BF16(af[i], bfv[j], acc[i][j], 0, 0, 0);
    }
  }

  const int r0 = m0 + wr * (BM / WR) + (lg << 2);
  const int c0 = n0 + wc * (BN / WC) + l15;
#pragma unroll
  for (int j = 0; j < BJ; j++) {
    const int col = c0 + j * 16;
    const float bv = bias[col];
#pragma unroll
    for (int i = 0; i < AI; i++) {
      const int row = r0 + i * 16;
#pragma unroll
      for (int r = 0; r < 4; r++) {
        float v = acc[i][j][r] + bv;
        if (RELU) v = fmaxf(v, 0.f);
        if (OUT_F32) ((float*)outp)[(size_t)(row + r) * N + col] = v;
        else         ((bf16_t*)outp)[(size_t)(row + r) * N + col] = (bf16_t)v;
      }
    }
  }
}

// ---------------- flash attention with T5 bias (QKV packed, stride 1536) ----------------
__global__ __launch_bounds__(256) void attn_k(const bf16_t* __restrict__ Q,
                                              const bf16_t* __restrict__ Kp,
                                              const bf16_t* __restrict__ Vp,
                                              const float* __restrict__ btab,
                                              const float* __restrict__ relb,
                                              bf16_t* __restrict__ ctx) {
  __shared__ __align__(16) bf16_t Ks[64 * 64];
  __shared__ __align__(16) bf16_t Vt[64 * 64];   // Vt[d][kv], XOR-swizzled
  __shared__ __align__(16) bf16_t Ps[4][16 * 64];
  const int tid = threadIdx.x;
  const int lane = tid & 63, wid = tid >> 6;
  const int q0 = blockIdx.x * 64;
  const int bb = blockIdx.y >> 3, h = blockIdx.y & 7;
  const size_t rbase = (size_t)bb * 2048 * 1536;
  const size_t cbase = (size_t)bb * 2048 * 512;
  const int hc = h * 64;
  const int l15 = lane & 15, lg = lane >> 4;
  const int srow = lane >> 3;
  const int scolx = ((lane & 7) ^ srow) * 8;

  const bf16_t* qp = Q + rbase + (size_t)(q0 + wid * 16 + l15) * 1536 + hc + lg * 8;
  bf16x8 qf0 = *(const bf16x8*)qp;
  bf16x8 qf1 = *(const bf16x8*)(qp + 32);

  float mrow[4], lrow[4];
  f32x4 acc[4];
#pragma unroll
  for (int j = 0; j < 4; j++) { mrow[j] = -3.0e38f; lrow[j] = 0.f; acc[j] = f32x4{0.f, 0.f, 0.f, 0.f}; }

  const float SCL = 0.125f * 1.44269504088896f;       // (1/sqrt(64))*log2(e)
  const float* bt = btab + (size_t)h * 4095 + 2047;
  const float cbp = relb[h * 32 + 15] * SCL;          // bucket 15: rel >= 91
  const float cbn = relb[h * 32 + 31] * SCL;          // bucket 31: rel <= -91
  char* pw = (char*)&Ps[wid][0];

  for (int kv0 = 0; kv0 < 2048; kv0 += 64) {
    __syncthreads();
    // K tile: global_load_lds with pre-swizzled source column
#pragma unroll
    for (int i = 0; i < 2; i++) {
      int r0 = wid * 16 + i * 8;
      gload_lds16(Kp + rbase + (size_t)(kv0 + r0 + srow) * 1536 + hc + scolx,
                  Ks + r0 * 64);
    }
    // V tile: reg transpose, wave handles d-chunk wid*16, lane = kv (swizzled writes)
    {
      const bf16_t* vs = Vp + rbase + (size_t)(kv0 + lane) * 1536 + hc + wid * 16;
      bf16x8 v0 = *(const bf16x8*)vs;
      bf16x8 v1 = *(const bf16x8*)(vs + 8);
#pragma unroll
      for (int j = 0; j < 8; j++) {
        *(bf16_t*)((char*)Vt + ((((wid * 16 + j) << 7) + lane * 2) ^ (j << 4))) = v0[j];
        *(bf16_t*)((char*)Vt + ((((wid * 16 + 8 + j) << 7) + lane * 2) ^ (j << 4))) = v1[j];
      }
    }
    asm volatile("s_waitcnt vmcnt(0)" ::: "memory");
    __syncthreads();

    // QK^T
    f32x4 s[4];
#pragma unroll
    for (int n = 0; n < 4; n++) s[n] = f32x4{0.f, 0.f, 0.f, 0.f};
#pragma unroll
    for (int ks = 0; ks < 2; ks++) {
      bf16x8 qf = ks ? qf1 : qf0;
      const int c2 = ks * 64 + lg * 16;
#pragma unroll
      for (int n = 0; n < 4; n++) {
        bf16x8 kf = lds_frag(Ks, n * 16 + l15, c2);
        s[n] = MFMA_BF16(qf, kf, s[n], 0, 0, 0);
      }
    }

    // logits in base-2 domain
    const int rq = q0 + wid * 16 + (lg << 2);
    const int ck = kv0 + l15;
    float lg2[4][4];
    const bool farp = (q0 - kv0) >= 192;    // min rel = 129 >= 91 -> bucket 15
    const bool farn = (kv0 - q0) >= 192;    // bucket 31
    if (farp || farn) {
      const float cb = farp ? cbp : cbn;
#pragma unroll
      for (int n = 0; n < 4; n++)
#pragma unroll
        for (int j = 0; j < 4; j++) lg2[n][j] = s[n][j] * SCL + cb;
    } else {
#pragma unroll
      for (int n = 0; n < 4; n++) {
        const float* btn = bt + (rq - (ck + n * 16));
#pragma unroll
        for (int j = 0; j < 4; j++) lg2[n][j] = (s[n][j] + btn[j]) * SCL;
      }
    }

    float mnew[4];
#pragma unroll
    for (int j = 0; j < 4; j++) {
      float mx = fmaxf(fmaxf(lg2[0][j], lg2[1][j]), fmaxf(lg2[2][j], lg2[3][j]));
      mnew[j] = fmaxf(mrow[j], mx);
    }
#pragma unroll
    for (int off = 1; off < 16; off <<= 1)
#pragma unroll
      for (int j = 0; j < 4; j++)
        mnew[j] = fmaxf(mnew[j], __shfl_xor(mnew[j], off, 64));

    float resc[4], psum[4];
#pragma unroll
    for (int j = 0; j < 4; j++) {
      resc[j] = exp2f(mrow[j] - mnew[j]);
      mrow[j] = mnew[j];
      psum[j] = 0.f;
    }
#pragma unroll
    for (int n = 0; n < 4; n++)
#pragma unroll
      for (int j = 0; j < 4; j++) {
        float p = exp2f(lg2[n][j] - mrow[j]);
        psum[j] += p;
        const int row = (lg << 2) + j;
        *(bf16_t*)(pw + (((row << 7) + (n * 16 + l15) * 2) ^ ((row & 7) << 4))) = (bf16_t)p;
      }
#pragma unroll
    for (int off = 1; off < 16; off <<= 1)
#pragma unroll
      for (int j = 0; j < 4; j++) psum[j] += __shfl_xor(psum[j], off, 64);
#pragma unroll
    for (int j = 0; j < 4; j++) lrow[j] = lrow[j] * resc[j] + psum[j];
#pragma unroll
    for (int dn = 0; dn < 4; dn++) {
      f32x4 t = acc[dn];
      t[0] *= resc[0]; t[1] *= resc[1]; t[2] *= resc[2]; t[3] *= resc[3];
      acc[dn] = t;
    }
    asm volatile("s_waitcnt lgkmcnt(0)" ::: "memory");
    // PV
#pragma unroll
    for (int ks = 0; ks < 2; ks++) {
      const int c2 = ks * 64 + lg * 16;
      bf16x8 pa = *(const bf16x8*)(pw + (((l15 << 7) + c2) ^ ((l15 & 7) << 4)));
#pragma unroll
      for (int dn = 0; dn < 4; dn++) {
        bf16x8 vf = lds_frag(Vt, dn * 16 + l15, c2);
        acc[dn] = MFMA_BF16(pa, vf, acc[dn], 0, 0, 0);
      }
    }
  }

  const int qr0 = q0 + wid * 16 + (lg << 2);
  float inv[4] = {1.f / lrow[0], 1.f / lrow[1], 1.f / lrow[2], 1.f / lrow[3]};
#pragma unroll
  for (int dn = 0; dn < 4; dn++)
#pragma unroll
    for (int j = 0; j < 4; j++)
      ctx[cbase + (size_t)(qr0 + j) * 512 + hc + dn * 16 + l15] = (bf16_t)(acc[dn][j] * inv[j]);
}

// ---------------- residual + LayerNorm ----------------
__global__ __launch_bounds__(256) void lnres_k(const float* __restrict__ a,
                                               const float* __restrict__ bsrc,
                                               const float* __restrict__ sc,
                                               const float* __restrict__ bi,
                                               float* __restrict__ outf,
                                               bf16_t* __restrict__ outb) {
  int row = blockIdx.x * 4 + (threadIdx.x >> 6);
  int lane = threadIdx.x & 63;
  size_t base = (size_t)row * 512 + lane * 8;
  float4 a0 = *(const float4*)(a + base), a1 = *(const float4*)(a + base + 4);
  float4 b0 = *(const float4*)(bsrc + base), b1 = *(const float4*)(bsrc + base + 4);
  float v[8] = {a0.x + b0.x, a0.y + b0.y, a0.z + b0.z, a0.w + b0.w,
                a1.x + b1.x, a1.y + b1.y, a1.z + b1.z, a1.w + b1.w};
  float s1 = 0.f, s2 = 0.f;
#pragma unroll
  for (int j = 0; j < 8; j++) { s1 += v[j]; s2 += v[j] * v[j]; }
#pragma unroll
  for (int off = 1; off < 64; off <<= 1) {
    s1 += __shfl_xor(s1, off, 64);
    s2 += __shfl_xor(s2, off, 64);
  }
  float mu = s1 * (1.f / 512.f);
  float var = s2 * (1.f / 512.f) - mu * mu;
  float rstd = rsqrtf(var + 1e-6f);
  int c = lane * 8;
  float4 sc0 = *(const float4*)(sc + c), sc1 = *(const float4*)(sc + c + 4);
  float4 bi0 = *(const float4*)(bi + c), bi1 = *(const float4*)(bi + c + 4);
  float scv[8] = {sc0.x, sc0.y, sc0.z, sc0.w, sc1.x, sc1.y, sc1.z, sc1.w};
  float biv[8] = {bi0.x, bi0.y, bi0.z, bi0.w, bi1.x, bi1.y, bi1.z, bi1.w};
  float o[8];
#pragma unroll
  for (int j = 0; j < 8; j++) o[j] = (v[j] - mu) * rstd * scv[j] + biv[j];
  *(float4*)(outf + base) = make_float4(o[0], o[1], o[2], o[3]);
  *(float4*)(outf + base + 4) = make_float4(o[4], o[5], o[6], o[7]);
  if (outb) {
    bf16x8 ob = {(bf16_t)o[0], (bf16_t)o[1], (bf16_t)o[2], (bf16_t)o[3],
                 (bf16_t)o[4], (bf16_t)o[5], (bf16_t)o[6], (bf16_t)o[7]};
    *(bf16x8*)(outb + base) = ob;
  }
}

// ---------------- host launcher ----------------
extern "C" void kernel_launch(void* const* d_in, const int* in_sizes, int n_in,
                              void* d_out, int out_size, void* d_ws, size_t ws_size,
                              hipStream_t stream) {
  const float* x    = (const float*)d_in[0];
  const float* Wq   = (const float*)d_in[1];
  const float* bq   = (const float*)d_in[2];
  const float* Wk   = (const float*)d_in[3];
  const float* bk   = (const float*)d_in[4];
  const float* Wv   = (const float*)d_in[5];
  const float* bv   = (const float*)d_in[6];
  const float* Wo   = (const float*)d_in[7];
  const float* bo   = (const float*)d_in[8];
  const float* relb = (const float*)d_in[9];
  const float* W1   = (const float*)d_in[10];
  const float* b1   = (const float*)d_in[11];
  const float* W2   = (const float*)d_in[12];
  const float* b2   = (const float*)d_in[13];
  const float* ln1s = (const float*)d_in[14];
  const float* ln1b = (const float*)d_in[15];
  const float* ln2s = (const float*)d_in[16];
  const float* ln2b = (const float*)d_in[17];

  char* w = (char*)d_ws;
  bf16_t* xb    = (bf16_t*)(w + 0);          //  8 MB [8192][512]; dead after QKV gemm
  bf16_t* qkv   = (bf16_t*)(w + 8388608);    // 24 MB [8192][1536]; dead after attn
  float*  tmpf  = (float*)(w + 8388608);     // 16 MB (Wo out; overlays dead qkv)
  bf16_t* ctxb  = (bf16_t*)(w + 33554432);   //  8 MB; dead after Wo
  float*  tmpf2 = (float*)(w + 33554432);    // 16 MB (FFN2 out; overlays dead ctxb)
  bf16_t* x1b   = (bf16_t*)(w + 41943040);   //  8 MB; dead after FFN1
  bf16_t* WqkvT = (bf16_t*)(w + 50331648);   // 1.5 MB [1536][512]
  bf16_t* WoT   = (bf16_t*)(w + 51904512);   // 0.5 MB
  bf16_t* W1T   = (bf16_t*)(w + 52428800);   //  2 MB [2048][512]
  bf16_t* W2T   = (bf16_t*)(w + 54525952);   //  2 MB [512][2048]
  float*  btab  = (float*)(w + 56623104);    // 128 KB [8][4095]
  float*  bqkv  = (float*)(w + 56885248);    //  6 KB
  float*  x1f   = (float*)(w + 56891392);    // 16 MB (ends ~70 MB)
  bf16_t* ffh   = (bf16_t*)(w + 0);          // 32 MB [8192][2048]; overlays xb+qkv/tmpf

  cvt_k<<<4096, 256, 0, stream>>>(x, xb, 8192 * 512 / 4);
  cvtT_k<<<dim3(8, 8), 256, 0, stream>>>(Wq, WqkvT, 512, 512);
  cvtT_k<<<dim3(8, 8), 256, 0, stream>>>(Wk, WqkvT + 512 * 512, 512, 512);
  cvtT_k<<<dim3(8, 8), 256, 0, stream>>>(Wv, WqkvT + 1024 * 512, 512, 512);
  cvtT_k<<<dim3(8, 8), 256, 0, stream>>>(Wo, WoT, 512, 512);
  cvtT_k<<<dim3(32, 8), 256, 0, stream>>>(W1, W1T, 512, 2048);
  cvtT_k<<<dim3(8, 32), 256, 0, stream>>>(W2, W2T, 2048, 512);
  relbias_k<<<128, 256, 0, stream>>>(relb, btab);
  cat3_k<<<6, 256, 0, stream>>>(bq, bk, bv, bqkv);

  // fused QKV projection: [8192][1536]
  gemm_k<128, 128, 2, 2, 0, 0><<<dim3(64, 12), 256, 0, stream>>>(xb, WqkvT, bqkv, qkv, 8192, 1536, 512);

  // attention (Q/K/V packed, stride 1536)
  attn_k<<<dim3(32, 32), 256, 0, stream>>>(qkv, qkv + 512, qkv + 1024, btab, relb, ctxb);

  // Wo + residual LN1
  gemm_k<64, 128, 1, 4, 1, 0><<<dim3(128, 4), 256, 0, stream>>>(ctxb, WoT, bo, tmpf, 8192, 512, 512);
  lnres_k<<<2048, 256, 0, stream>>>(x, tmpf, ln1s, ln1b, x1f, x1b);

  // FFN
  gemm_k<128, 128, 2, 2, 0, 1><<<dim3(64, 16), 256, 0, stream>>>(x1b, W1T, b1, ffh, 8192, 2048, 512);
  gemm_k<64, 128, 1, 4, 1, 0><<<dim3(128, 4), 256, 0, stream>>>(ffh, W2T, b2, tmpf2, 8192, 512, 2048);
  lnres_k<<<2048, 256, 0, stream>>>(x1f, tmpf2, ln2s, ln2b, (float*)d_out, (bf16_t*)nullptr);
}

// Round 3
// 262.792 us; speedup vs baseline: 1.4000x; 1.1638x over previous
//
// T5 encoder layer — round 3: swapped-QK in-register softmax (T12-style),
// V^T precomputed by GEMM, 2-phase prefetch double-buffered attn (T3-min),
// defer-max (T13).
#include <hip/hip_runtime.h>

typedef __bf16 bf16_t;
typedef __bf16 bf16x8 __attribute__((ext_vector_type(8)));
typedef __bf16 bf16x4 __attribute__((ext_vector_type(4)));
typedef float  f32x4  __attribute__((ext_vector_type(4)));

#define MFMA_BF16 __builtin_amdgcn_mfma_f32_16x16x32_bf16

__device__ __forceinline__ void gload_lds16(const void* g, void* l) {
  __builtin_amdgcn_global_load_lds((const __attribute__((address_space(1))) void*)g,
                                   (__attribute__((address_space(3))) void*)l,
                                   16, 0, 0);
}

// swizzled fragment read from a [rows][64-bf16] LDS tile (128B rows).
__device__ __forceinline__ bf16x8 lds_frag(const bf16_t* base, int row, int c2) {
  return *(const bf16x8*)((const char*)base + ((((row) << 7) + c2) ^ ((row & 7) << 4)));
}

// ---------------- f32 -> bf16 flat convert ----------------
__global__ __launch_bounds__(256) void cvt_k(const float* __restrict__ s,
                                             bf16_t* __restrict__ d, int n4) {
  int i = blockIdx.x * 256 + threadIdx.x;
  if (i >= n4) return;
  float4 v = ((const float4*)s)[i];
  bf16x4 o = { (bf16_t)v.x, (bf16_t)v.y, (bf16_t)v.z, (bf16_t)v.w };
  ((bf16x4*)d)[i] = o;
}

// ---------------- f32 [K][N] -> bf16 [N][K] transpose-convert ----------------
__global__ __launch_bounds__(256) void cvtT_k(const float* __restrict__ src,
                                              bf16_t* __restrict__ dst,
                                              int K, int N) {
  __shared__ float t[64][65];
  int n0 = blockIdx.x * 64, k0 = blockIdx.y * 64;
  int tx = threadIdx.x & 63, g = threadIdx.x >> 6;
#pragma unroll
  for (int i = g; i < 64; i += 4) t[i][tx] = src[(size_t)(k0 + i) * N + n0 + tx];
  __syncthreads();
#pragma unroll
  for (int i = g; i < 64; i += 4)
    dst[(size_t)(n0 + i) * K + k0 + tx] = (bf16_t)t[tx][i];
}

// ---------------- T5 bias table (pre-scaled by 1/8*log2e): bt[h][(q-k)+2047] ----------------
__global__ __launch_bounds__(256) void relbias_k(const float* __restrict__ rb,
                                                 float* __restrict__ bt) {
  const float SCL = 0.125f * 1.44269504088896f;
  int i = blockIdx.x * 256 + threadIdx.x;
  if (i >= 8 * 4095) return;
  int h = i / 4095;
  int r = (i % 4095) - 2047;
  int ret = (r < 0) ? 16 : 0;
  int n = (r < 0) ? -r : r;
  int b;
  if (n < 8) b = n;
  else {
    float v = logf((float)n / 8.0f) / logf(16.0f) * 8.0f;
    int vi = 8 + (int)v;
    b = vi < 15 ? vi : 15;
  }
  bt[i] = rb[h * 32 + ret + b] * SCL;
}

// ---------------- concat 2x512 f32 ----------------
__global__ __launch_bounds__(256) void cat2_k(const float* __restrict__ a,
                                              const float* __restrict__ b,
                                              float* __restrict__ o) {
  int i = blockIdx.x * 256 + threadIdx.x;
  if (i >= 1024) return;
  o[i] = (i < 512) ? a[i] : b[i - 512];
}

// ---------------- bf16 MFMA GEMM with T2 swizzle ----------------
// C[M][N] = A[M][K] @ Bt[N][K]^T + bias.  BMxBN tile, BK=64, 4 waves (WRxWC).
template <int BM, int BN, int WR, int WC, int OUT_F32, int RELU, int BIASROW>
__global__ __launch_bounds__(256) void gemm_k(const bf16_t* __restrict__ A,
                                              const bf16_t* __restrict__ Bt,
                                              const float* __restrict__ bias,
                                              void* __restrict__ outp,
                                              int M, int N, int K) {
  constexpr int AI = BM / WR / 16;
  constexpr int BJ = BN / WC / 16;
  __shared__ __align__(16) bf16_t As[BM * 64];
  __shared__ __align__(16) bf16_t Bs[BN * 64];
  const int tid = threadIdx.x;
  const int lane = tid & 63, wid = tid >> 6;
  const int m0 = blockIdx.x * BM, n0 = blockIdx.y * BN;
  const int wr = wid / WC, wc = wid % WC;
  const int l15 = lane & 15, lg = lane >> 4;
  const int srow = lane >> 3;
  const int scolx = ((lane & 7) ^ srow) * 8;   // pre-swizzled source column

  f32x4 acc[AI][BJ];
#pragma unroll
  for (int i = 0; i < AI; i++)
#pragma unroll
    for (int j = 0; j < BJ; j++) acc[i][j] = f32x4{0.f, 0.f, 0.f, 0.f};

  const bf16_t* Ag = A + (size_t)(m0 + wid * (BM / 4) + srow) * K + scolx;
  const bf16_t* Bg = Bt + (size_t)(n0 + wid * (BN / 4) + srow) * K + scolx;
  bf16_t* Al = As + wid * (BM / 4) * 64;
  bf16_t* Bl = Bs + wid * (BN / 4) * 64;

  for (int k0 = 0; k0 < K; k0 += 64) {
    __syncthreads();
#pragma unroll
    for (int i = 0; i < BM / 32; i++)
      gload_lds16(Ag + (size_t)i * 8 * K + k0, Al + i * 8 * 64);
#pragma unroll
    for (int i = 0; i < BN / 32; i++)
      gload_lds16(Bg + (size_t)i * 8 * K + k0, Bl + i * 8 * 64);
    asm volatile("s_waitcnt vmcnt(0)" ::: "memory");
    __syncthreads();
#pragma unroll
    for (int ks = 0; ks < 2; ks++) {
      const int c2 = ks * 64 + lg * 16;
      bf16x8 af[AI], bfv[BJ];
#pragma unroll
      for (int i = 0; i < AI; i++)
        af[i] = lds_frag(As, wr * (BM / WR) + i * 16 + l15, c2);
#pragma unroll
      for (int j = 0; j < BJ; j++)
        bfv[j] = lds_frag(Bs, wc * (BN / WC) + j * 16 + l15, c2);
#pragma unroll
      for (int i = 0; i < AI; i++)
#pragma unroll
        for (int j = 0; j < BJ; j++)
          acc[i][j] = MFMA_BF16(af[i], bfv[j], acc[i][j], 0, 0, 0);
    }
  }

  const int r0 = m0 + wr * (BM / WR) + (lg << 2);
  const int c0 = n0 + wc * (BN / WC) + l15;
#pragma unroll
  for (int j = 0; j < BJ; j++) {
    const int col = c0 + j * 16;
    const float bvc = BIASROW ? 0.f : bias[col];
#pragma unroll
    for (int i = 0; i < AI; i++) {
      const int row = r0 + i * 16;
#pragma unroll
      for (int r = 0; r < 4; r++) {
        float v = acc[i][j][r] + (BIASROW ? bias[row + r] : bvc);
        if (RELU) v = fmaxf(v, 0.f);
        if (OUT_F32) ((float*)outp)[(size_t)(row + r) * N + col] = v;
        else         ((bf16_t*)outp)[(size_t)(row + r) * N + col] = (bf16_t)v;
      }
    }
  }
}

// ---------------- flash attention, swapped-QK in-register softmax ----------------
// Q/K packed stride 1024; Vt is global [512][8192] (row = h*64+d, col = b*2048+s).
__global__ __launch_bounds__(256) void attn_k(const bf16_t* __restrict__ Q,
                                              const bf16_t* __restrict__ Kp,
                                              const bf16_t* __restrict__ Vt,
                                              const float* __restrict__ btabS,
                                              const float* __restrict__ relb,
                                              bf16_t* __restrict__ ctx) {
  __shared__ __align__(16) bf16_t Ks[2][64 * 64];
  __shared__ __align__(16) bf16_t Vs[2][64 * 64];
  __shared__ __align__(16) bf16_t Ps[4][16 * 64];
  const int tid = threadIdx.x;
  const int lane = tid & 63, wid = tid >> 6;
  const int q0 = blockIdx.x * 64;
  const int bb = blockIdx.y >> 3, h = blockIdx.y & 7;
  const size_t qkbase = (size_t)bb * 2048 * 1024;
  const size_t cbase = (size_t)bb * 2048 * 512;
  const int hc = h * 64;
  const int l15 = lane & 15, lg = lane >> 4;
  const int srow = lane >> 3;
  const int scolx = ((lane & 7) ^ srow) * 8;

  // Q fragment (B-operand): row(j)=l15 -> q, k = lg*8 + e
  const bf16_t* qp = Q + qkbase + (size_t)(q0 + wid * 16 + l15) * 1024 + hc + lg * 8;
  bf16x8 qf0 = *(const bf16x8*)qp;
  bf16x8 qf1 = *(const bf16x8*)(qp + 32);

  const float SCL = 0.125f * 1.44269504088896f;
  const float* bt = btabS + (size_t)h * 4095 + 2047;
  const float cbp = relb[h * 32 + 15] * SCL;
  const float cbn = relb[h * 32 + 31] * SCL;

  float mrow = -1.0e30f, lrow = 0.f;     // stats for q = q0 + wid*16 + l15
  f32x4 acc[4];
#pragma unroll
  for (int dn = 0; dn < 4; dn++) acc[dn] = f32x4{0.f, 0.f, 0.f, 0.f};
  char* pw = (char*)&Ps[wid][0];
  const int rq = q0 + wid * 16 + l15;

  // staging: this wave loads K rows [wid*16, +16) and Vt rows [hc+wid*16, +16)
  const bf16_t* kg = Kp + qkbase + (size_t)(wid * 16 + srow) * 1024 + hc + scolx;
  const bf16_t* vg = Vt + (size_t)(hc + wid * 16 + srow) * 8192 + bb * 2048 + scolx;
  bf16_t* kl0 = &Ks[0][wid * 16 * 64];
  bf16_t* vl0 = &Vs[0][wid * 16 * 64];

#define STAGE(buf, kv0)                                                          \
  do {                                                                           \
    gload_lds16(kg + (size_t)(kv0) * 1024, kl0 + (buf) * 64 * 64);               \
    gload_lds16(kg + (size_t)((kv0) + 8) * 1024, kl0 + (buf) * 64 * 64 + 8 * 64);\
    gload_lds16(vg + (kv0), vl0 + (buf) * 64 * 64);                              \
    gload_lds16(vg + (kv0) + 8 * 8192, vl0 + (buf) * 64 * 64 + 8 * 64);          \
  } while (0)

  STAGE(0, 0);
  asm volatile("s_waitcnt vmcnt(0)" ::: "memory");
  __syncthreads();

  for (int t = 0; t < 32; t++) {
    const int kv0 = t * 64;
    const int buf = t & 1;
    if (t < 31) STAGE(buf ^ 1, kv0 + 64);

    const bf16_t* KsB = &Ks[buf][0];
    const bf16_t* VsB = &Vs[buf][0];

    // QK^T swapped: s[n] row = kv (n*16 + lg*4 + r), col = q (= l15)
    f32x4 s[4];
#pragma unroll
    for (int n = 0; n < 4; n++) s[n] = f32x4{0.f, 0.f, 0.f, 0.f};
#pragma unroll
    for (int ks = 0; ks < 2; ks++) {
      bf16x8 qf = ks ? qf1 : qf0;
      const int c2 = ks * 64 + lg * 16;
#pragma unroll
      for (int n = 0; n < 4; n++) {
        bf16x8 kf = lds_frag(KsB, n * 16 + l15, c2);
        s[n] = MFMA_BF16(kf, qf, s[n], 0, 0, 0);
      }
    }

    // logits (base-2, pre-scaled bias)
    float lg2[4][4];
    const bool farp = (q0 - kv0) >= 192;
    const bool farn = (kv0 - q0) >= 192;
    if (farp || farn) {
      const float cb = farp ? cbp : cbn;
#pragma unroll
      for (int n = 0; n < 4; n++)
#pragma unroll
        for (int r = 0; r < 4; r++) lg2[n][r] = s[n][r] * SCL + cb;
    } else {
#pragma unroll
      for (int n = 0; n < 4; n++) {
        const float* btn = bt + (rq - kv0 - n * 16 - lg * 4);
#pragma unroll
        for (int r = 0; r < 4; r++) lg2[n][r] = s[n][r] * SCL + btn[-r];
      }
    }

    // row max: 15 in-lane + 2 shuffles (lanes same l15 across lg)
    float tmax = lg2[0][0];
#pragma unroll
    for (int n = 0; n < 4; n++)
#pragma unroll
      for (int r = 0; r < 4; r++) tmax = fmaxf(tmax, lg2[n][r]);
    tmax = fmaxf(tmax, __shfl_xor(tmax, 16, 64));
    tmax = fmaxf(tmax, __shfl_xor(tmax, 32, 64));

    // defer-max (T13, THR=8)
    if (!__all(tmax - mrow <= 8.0f)) {
      float mnew = fmaxf(mrow, tmax);
      float rs = exp2f(mrow - mnew);
      mrow = mnew;
      lrow *= rs;
      float rr0 = __shfl(rs, (lg << 2) + 0, 64);
      float rr1 = __shfl(rs, (lg << 2) + 1, 64);
      float rr2 = __shfl(rs, (lg << 2) + 2, 64);
      float rr3 = __shfl(rs, (lg << 2) + 3, 64);
#pragma unroll
      for (int dn = 0; dn < 4; dn++) {
        f32x4 a = acc[dn];
        a[0] *= rr0; a[1] *= rr1; a[2] *= rr2; a[3] *= rr3;
        acc[dn] = a;
      }
    }

    // P = exp2(lg2 - m); pack pairs and store to word-permuted Ps
    float psum = 0.f;
#pragma unroll
    for (int n = 0; n < 4; n++) {
      float p0 = exp2f(lg2[n][0] - mrow);
      float p1 = exp2f(lg2[n][1] - mrow);
      float p2 = exp2f(lg2[n][2] - mrow);
      float p3 = exp2f(lg2[n][3] - mrow);
      psum += (p0 + p1) + (p2 + p3);
      unsigned w0, w1;
      asm("v_cvt_pk_bf16_f32 %0, %1, %2" : "=v"(w0) : "v"(p0), "v"(p1));
      asm("v_cvt_pk_bf16_f32 %0, %1, %2" : "=v"(w1) : "v"(p2), "v"(p3));
      // word layout f(n,lg,i) = n*8 + (lg>>1)*4 + (lg&1)*2 + i  (row = l15)
      uint2 wv = {w0, w1};
      *(uint2*)(pw + (((l15 << 7) + n * 32 + (lg >> 1) * 16 + (lg & 1) * 8)
                      ^ ((l15 & 7) << 4))) = wv;
    }
    psum += __shfl_xor(psum, 16, 64);
    psum += __shfl_xor(psum, 32, 64);
    lrow += psum;

    asm volatile("s_waitcnt lgkmcnt(0)" ::: "memory");
    __builtin_amdgcn_sched_barrier(0);

    // PV: A = P (row=q=l15, k = ks*32+lg*8+e), B = Vt rows d
#pragma unroll
    for (int ks = 0; ks < 2; ks++) {
      const int c2 = ks * 64 + lg * 16;
      bf16x8 pa = *(const bf16x8*)(pw + (((l15 << 7) + ks * 64 + (lg >> 1) * 32 + (lg & 1) * 16)
                                         ^ ((l15 & 7) << 4)));
#pragma unroll
      for (int dn = 0; dn < 4; dn++) {
        bf16x8 vf = lds_frag(VsB, dn * 16 + l15, c2);
        acc[dn] = MFMA_BF16(pa, vf, acc[dn], 0, 0, 0);
      }
    }

    asm volatile("s_waitcnt vmcnt(0)" ::: "memory");
    __syncthreads();
  }
#undef STAGE

  // epilogue: acc row = q-index lg*4+r, col = d = dn*16 + l15
  float li0 = __shfl(lrow, (lg << 2) + 0, 64);
  float li1 = __shfl(lrow, (lg << 2) + 1, 64);
  float li2 = __shfl(lrow, (lg << 2) + 2, 64);
  float li3 = __shfl(lrow, (lg << 2) + 3, 64);
  float inv[4] = {1.f / li0, 1.f / li1, 1.f / li2, 1.f / li3};
  const int qr0 = q0 + wid * 16 + (lg << 2);
#pragma unroll
  for (int dn = 0; dn < 4; dn++)
#pragma unroll
    for (int r = 0; r < 4; r++)
      ctx[cbase + (size_t)(qr0 + r) * 512 + hc + dn * 16 + l15] = (bf16_t)(acc[dn][r] * inv[r]);
}

// ---------------- residual + LayerNorm ----------------
__global__ __launch_bounds__(256) void lnres_k(const float* __restrict__ a,
                                               const float* __restrict__ bsrc,
                                               const float* __restrict__ sc,
                                               const float* __restrict__ bi,
                                               float* __restrict__ outf,
                                               bf16_t* __restrict__ outb) {
  int row = blockIdx.x * 4 + (threadIdx.x >> 6);
  int lane = threadIdx.x & 63;
  size_t base = (size_t)row * 512 + lane * 8;
  float4 a0 = *(const float4*)(a + base), a1 = *(const float4*)(a + base + 4);
  float4 b0 = *(const float4*)(bsrc + base), b1 = *(const float4*)(bsrc + base + 4);
  float v[8] = {a0.x + b0.x, a0.y + b0.y, a0.z + b0.z, a0.w + b0.w,
                a1.x + b1.x, a1.y + b1.y, a1.z + b1.z, a1.w + b1.w};
  float s1 = 0.f, s2 = 0.f;
#pragma unroll
  for (int j = 0; j < 8; j++) { s1 += v[j]; s2 += v[j] * v[j]; }
#pragma unroll
  for (int off = 1; off < 64; off <<= 1) {
    s1 += __shfl_xor(s1, off, 64);
    s2 += __shfl_xor(s2, off, 64);
  }
  float mu = s1 * (1.f / 512.f);
  float var = s2 * (1.f / 512.f) - mu * mu;
  float rstd = rsqrtf(var + 1e-6f);
  int c = lane * 8;
  float4 sc0 = *(const float4*)(sc + c), sc1 = *(const float4*)(sc + c + 4);
  float4 bi0 = *(const float4*)(bi + c), bi1 = *(const float4*)(bi + c + 4);
  float scv[8] = {sc0.x, sc0.y, sc0.z, sc0.w, sc1.x, sc1.y, sc1.z, sc1.w};
  float biv[8] = {bi0.x, bi0.y, bi0.z, bi0.w, bi1.x, bi1.y, bi1.z, bi1.w};
  float o[8];
#pragma unroll
  for (int j = 0; j < 8; j++) o[j] = (v[j] - mu) * rstd * scv[j] + biv[j];
  *(float4*)(outf + base) = make_float4(o[0], o[1], o[2], o[3]);
  *(float4*)(outf + base + 4) = make_float4(o[4], o[5], o[6], o[7]);
  if (outb) {
    bf16x8 ob = {(bf16_t)o[0], (bf16_t)o[1], (bf16_t)o[2], (bf16_t)o[3],
                 (bf16_t)o[4], (bf16_t)o[5], (bf16_t)o[6], (bf16_t)o[7]};
    *(bf16x8*)(outb + base) = ob;
  }
}

// ---------------- host launcher ----------------
extern "C" void kernel_launch(void* const* d_in, const int* in_sizes, int n_in,
                              void* d_out, int out_size, void* d_ws, size_t ws_size,
                              hipStream_t stream) {
  const float* x    = (const float*)d_in[0];
  const float* Wq   = (const float*)d_in[1];
  const float* bq   = (const float*)d_in[2];
  const float* Wk   = (const float*)d_in[3];
  const float* bk   = (const float*)d_in[4];
  const float* Wv   = (const float*)d_in[5];
  const float* bv   = (const float*)d_in[6];
  const float* Wo   = (const float*)d_in[7];
  const float* bo   = (const float*)d_in[8];
  const float* relb = (const float*)d_in[9];
  const float* W1   = (const float*)d_in[10];
  const float* b1   = (const float*)d_in[11];
  const float* W2   = (const float*)d_in[12];
  const float* b2   = (const float*)d_in[13];
  const float* ln1s = (const float*)d_in[14];
  const float* ln1b = (const float*)d_in[15];
  const float* ln2s = (const float*)d_in[16];
  const float* ln2b = (const float*)d_in[17];

  char* w = (char*)d_ws;
  bf16_t* xb    = (bf16_t*)(w + 0);          //  8 MB [8192][512]; dead after QK/Vt gemms
  bf16_t* qk    = (bf16_t*)(w + 8388608);    // 16 MB [8192][1024]; dead after attn
  bf16_t* vtg   = (bf16_t*)(w + 25165824);   //  8 MB [512][8192]; dead after attn
  bf16_t* ctxb  = (bf16_t*)(w + 33554432);   //  8 MB; dead after Wo
  float*  tmpf2 = (float*)(w + 33554432);    // 16 MB (FFN2 out; overlays dead ctxb)
  bf16_t* x1b   = (bf16_t*)(w + 50331648);   //  8 MB
  bf16_t* WqkT  = (bf16_t*)(w + 58720256);   //  1 MB [1024][512]
  bf16_t* WvT   = (bf16_t*)(w + 59768832);   // 0.5 MB
  bf16_t* WoT   = (bf16_t*)(w + 60293120);   // 0.5 MB
  bf16_t* W1T   = (bf16_t*)(w + 60817408);   //  2 MB [2048][512]
  bf16_t* W2T   = (bf16_t*)(w + 62914560);   //  2 MB [512][2048]
  float*  btab  = (float*)(w + 65011712);    // 128 KB
  float*  bqk   = (float*)(w + 65273856);    //  4 KB
  float*  x1f   = (float*)(w + 65798144);    // 16 MB
  float*  tmpf  = (float*)(w + 82575360);    // 16 MB (Wo out) -> ends ~99 MB? keep at 82.5+16=98.5MB
  bf16_t* ffh   = (bf16_t*)(w + 0);          // 32 MB [8192][2048]; overlays xb+qk+vtg

  cvt_k<<<4096, 256, 0, stream>>>(x, xb, 8192 * 512 / 4);
  cvtT_k<<<dim3(8, 8), 256, 0, stream>>>(Wq, WqkT, 512, 512);
  cvtT_k<<<dim3(8, 8), 256, 0, stream>>>(Wk, WqkT + 512 * 512, 512, 512);
  cvtT_k<<<dim3(8, 8), 256, 0, stream>>>(Wv, WvT, 512, 512);
  cvtT_k<<<dim3(8, 8), 256, 0, stream>>>(Wo, WoT, 512, 512);
  cvtT_k<<<dim3(32, 8), 256, 0, stream>>>(W1, W1T, 512, 2048);
  cvtT_k<<<dim3(8, 32), 256, 0, stream>>>(W2, W2T, 2048, 512);
  relbias_k<<<128, 256, 0, stream>>>(relb, btab);
  cat2_k<<<4, 256, 0, stream>>>(bq, bk, bqk);

  // QK projection [8192][1024]
  gemm_k<128, 128, 2, 2, 0, 0, 0><<<dim3(64, 8), 256, 0, stream>>>(xb, WqkT, bqk, qk, 8192, 1024, 512);
  // V^T projection: Vt[dout][seq] = WvT @ xb^T  (row bias bv)
  gemm_k<128, 128, 2, 2, 0, 0, 1><<<dim3(4, 64), 256, 0, stream>>>(WvT, xb, bv, vtg, 512, 8192, 512);

  // attention
  attn_k<<<dim3(32, 32), 256, 0, stream>>>(qk, qk + 512, vtg, btab, relb, ctxb);

  // Wo + residual LN1
  gemm_k<64, 128, 1, 4, 1, 0, 0><<<dim3(128, 4), 256, 0, stream>>>(ctxb, WoT, bo, tmpf, 8192, 512, 512);
  lnres_k<<<2048, 256, 0, stream>>>(x, tmpf, ln1s, ln1b, x1f, x1b);

  // FFN
  gemm_k<128, 128, 2, 2, 0, 1, 0><<<dim3(64, 16), 256, 0, stream>>>(x1b, W1T, b1, ffh, 8192, 2048, 512);
  gemm_k<64, 128, 1, 4, 1, 0, 0><<<dim3(128, 4), 256, 0, stream>>>(ffh, W2T, b2, tmpf2, 8192, 512, 2048);
  lnres_k<<<2048, 256, 0, stream>>>(x1f, tmpf2, ln2s, ln2b, (float*)d_out, (bf16_t*)nullptr);
}

// Round 4
// 231.379 us; speedup vs baseline: 1.5901x; 1.1358x over previous
//
// T5 encoder layer — round 4: attn 8-wave QBLK=128, 3-buffer counted-vmcnt
// pipeline (T4), setprio (T5); Vt gemm retiled 64x128.
#include <hip/hip_runtime.h>

typedef __bf16 bf16_t;
typedef __bf16 bf16x8 __attribute__((ext_vector_type(8)));
typedef __bf16 bf16x4 __attribute__((ext_vector_type(4)));
typedef float  f32x4  __attribute__((ext_vector_type(4)));

#define MFMA_BF16 __builtin_amdgcn_mfma_f32_16x16x32_bf16

__device__ __forceinline__ void gload_lds16(const void* g, void* l) {
  __builtin_amdgcn_global_load_lds((const __attribute__((address_space(1))) void*)g,
                                   (__attribute__((address_space(3))) void*)l,
                                   16, 0, 0);
}

// swizzled fragment read from a [rows][64-bf16] LDS tile (128B rows).
__device__ __forceinline__ bf16x8 lds_frag(const bf16_t* base, int row, int c2) {
  return *(const bf16x8*)((const char*)base + ((((row) << 7) + c2) ^ ((row & 7) << 4)));
}

// ---------------- f32 -> bf16 flat convert ----------------
__global__ __launch_bounds__(256) void cvt_k(const float* __restrict__ s,
                                             bf16_t* __restrict__ d, int n4) {
  int i = blockIdx.x * 256 + threadIdx.x;
  if (i >= n4) return;
  float4 v = ((const float4*)s)[i];
  bf16x4 o = { (bf16_t)v.x, (bf16_t)v.y, (bf16_t)v.z, (bf16_t)v.w };
  ((bf16x4*)d)[i] = o;
}

// ---------------- f32 [K][N] -> bf16 [N][K] transpose-convert ----------------
__global__ __launch_bounds__(256) void cvtT_k(const float* __restrict__ src,
                                              bf16_t* __restrict__ dst,
                                              int K, int N) {
  __shared__ float t[64][65];
  int n0 = blockIdx.x * 64, k0 = blockIdx.y * 64;
  int tx = threadIdx.x & 63, g = threadIdx.x >> 6;
#pragma unroll
  for (int i = g; i < 64; i += 4) t[i][tx] = src[(size_t)(k0 + i) * N + n0 + tx];
  __syncthreads();
#pragma unroll
  for (int i = g; i < 64; i += 4)
    dst[(size_t)(n0 + i) * K + k0 + tx] = (bf16_t)t[tx][i];
}

// ---------------- T5 bias table (pre-scaled by 1/8*log2e): bt[h][(q-k)+2047] ----------------
__global__ __launch_bounds__(256) void relbias_k(const float* __restrict__ rb,
                                                 float* __restrict__ bt) {
  const float SCL = 0.125f * 1.44269504088896f;
  int i = blockIdx.x * 256 + threadIdx.x;
  if (i >= 8 * 4095) return;
  int h = i / 4095;
  int r = (i % 4095) - 2047;
  int ret = (r < 0) ? 16 : 0;
  int n = (r < 0) ? -r : r;
  int b;
  if (n < 8) b = n;
  else {
    float v = logf((float)n / 8.0f) / logf(16.0f) * 8.0f;
    int vi = 8 + (int)v;
    b = vi < 15 ? vi : 15;
  }
  bt[i] = rb[h * 32 + ret + b] * SCL;
}

// ---------------- concat 2x512 f32 ----------------
__global__ __launch_bounds__(256) void cat2_k(const float* __restrict__ a,
                                              const float* __restrict__ b,
                                              float* __restrict__ o) {
  int i = blockIdx.x * 256 + threadIdx.x;
  if (i >= 1024) return;
  o[i] = (i < 512) ? a[i] : b[i - 512];
}

// ---------------- bf16 MFMA GEMM with T2 swizzle ----------------
// C[M][N] = A[M][K] @ Bt[N][K]^T + bias.  BMxBN tile, BK=64, 4 waves (WRxWC).
template <int BM, int BN, int WR, int WC, int OUT_F32, int RELU, int BIASROW>
__global__ __launch_bounds__(256) void gemm_k(const bf16_t* __restrict__ A,
                                              const bf16_t* __restrict__ Bt,
                                              const float* __restrict__ bias,
                                              void* __restrict__ outp,
                                              int M, int N, int K) {
  constexpr int AI = BM / WR / 16;
  constexpr int BJ = BN / WC / 16;
  __shared__ __align__(16) bf16_t As[BM * 64];
  __shared__ __align__(16) bf16_t Bs[BN * 64];
  const int tid = threadIdx.x;
  const int lane = tid & 63, wid = tid >> 6;
  const int m0 = blockIdx.x * BM, n0 = blockIdx.y * BN;
  const int wr = wid / WC, wc = wid % WC;
  const int l15 = lane & 15, lg = lane >> 4;
  const int srow = lane >> 3;
  const int scolx = ((lane & 7) ^ srow) * 8;   // pre-swizzled source column

  f32x4 acc[AI][BJ];
#pragma unroll
  for (int i = 0; i < AI; i++)
#pragma unroll
    for (int j = 0; j < BJ; j++) acc[i][j] = f32x4{0.f, 0.f, 0.f, 0.f};

  const bf16_t* Ag = A + (size_t)(m0 + wid * (BM / 4) + srow) * K + scolx;
  const bf16_t* Bg = Bt + (size_t)(n0 + wid * (BN / 4) + srow) * K + scolx;
  bf16_t* Al = As + wid * (BM / 4) * 64;
  bf16_t* Bl = Bs + wid * (BN / 4) * 64;

  for (int k0 = 0; k0 < K; k0 += 64) {
    __syncthreads();
#pragma unroll
    for (int i = 0; i < BM / 32; i++)
      gload_lds16(Ag + (size_t)i * 8 * K + k0, Al + i * 8 * 64);
#pragma unroll
    for (int i = 0; i < BN / 32; i++)
      gload_lds16(Bg + (size_t)i * 8 * K + k0, Bl + i * 8 * 64);
    asm volatile("s_waitcnt vmcnt(0)" ::: "memory");
    __syncthreads();
#pragma unroll
    for (int ks = 0; ks < 2; ks++) {
      const int c2 = ks * 64 + lg * 16;
      bf16x8 af[AI], bfv[BJ];
#pragma unroll
      for (int i = 0; i < AI; i++)
        af[i] = lds_frag(As, wr * (BM / WR) + i * 16 + l15, c2);
#pragma unroll
      for (int j = 0; j < BJ; j++)
        bfv[j] = lds_frag(Bs, wc * (BN / WC) + j * 16 + l15, c2);
#pragma unroll
      for (int i = 0; i < AI; i++)
#pragma unroll
        for (int j = 0; j < BJ; j++)
          acc[i][j] = MFMA_BF16(af[i], bfv[j], acc[i][j], 0, 0, 0);
    }
  }

  const int r0 = m0 + wr * (BM / WR) + (lg << 2);
  const int c0 = n0 + wc * (BN / WC) + l15;
#pragma unroll
  for (int j = 0; j < BJ; j++) {
    const int col = c0 + j * 16;
    const float bvc = BIASROW ? 0.f : bias[col];
#pragma unroll
    for (int i = 0; i < AI; i++) {
      const int row = r0 + i * 16;
#pragma unroll
      for (int r = 0; r < 4; r++) {
        float v = acc[i][j][r] + (BIASROW ? bias[row + r] : bvc);
        if (RELU) v = fmaxf(v, 0.f);
        if (OUT_F32) ((float*)outp)[(size_t)(row + r) * N + col] = v;
        else         ((bf16_t*)outp)[(size_t)(row + r) * N + col] = (bf16_t)v;
      }
    }
  }
}

// ---------------- flash attention: 8 waves, QBLK=128, 3-buffer pipeline ----------------
// Q/K packed stride 1024; Vt is global [512][8192] (row = h*64+d, col = b*2048+s).
__global__ __launch_bounds__(512) void attn_k(const bf16_t* __restrict__ Q,
                                              const bf16_t* __restrict__ Kp,
                                              const bf16_t* __restrict__ Vt,
                                              const float* __restrict__ btabS,
                                              const float* __restrict__ relb,
                                              bf16_t* __restrict__ ctx) {
  __shared__ __align__(16) bf16_t Ks[3][64 * 64];
  __shared__ __align__(16) bf16_t Vs[3][64 * 64];
  __shared__ __align__(16) bf16_t Ps[8][16 * 64];
  const int tid = threadIdx.x;
  const int lane = tid & 63, wid = tid >> 6;
  const int q0 = blockIdx.x * 128;
  const int bb = blockIdx.y >> 3, h = blockIdx.y & 7;
  const size_t qkbase = (size_t)bb * 2048 * 1024;
  const size_t cbase = (size_t)bb * 2048 * 512;
  const int hc = h * 64;
  const int l15 = lane & 15, lg = lane >> 4;
  const int srow = lane >> 3;
  const int scolx = ((lane & 7) ^ srow) * 8;

  // Q fragment (B-operand): row(j)=l15 -> q, k = lg*8 + e
  const bf16_t* qp = Q + qkbase + (size_t)(q0 + wid * 16 + l15) * 1024 + hc + lg * 8;
  bf16x8 qf0 = *(const bf16x8*)qp;
  bf16x8 qf1 = *(const bf16x8*)(qp + 32);

  const float SCL = 0.125f * 1.44269504088896f;
  const float* bt = btabS + (size_t)h * 4095 + 2047;
  const float cbp = relb[h * 32 + 15] * SCL;
  const float cbn = relb[h * 32 + 31] * SCL;

  float mrow = -1.0e30f, lrow = 0.f;     // stats for q = q0 + wid*16 + l15
  f32x4 acc[4];
#pragma unroll
  for (int dn = 0; dn < 4; dn++) acc[dn] = f32x4{0.f, 0.f, 0.f, 0.f};
  char* pw = (char*)&Ps[wid][0];
  const int rq = q0 + wid * 16 + l15;

  // staging: wave wid loads K rows [wid*8, +8) and Vt d-rows [wid*8, +8)
  const bf16_t* kg = Kp + qkbase + (size_t)(wid * 8 + srow) * 1024 + hc + scolx;
  const bf16_t* vg = Vt + (size_t)(hc + wid * 8 + srow) * 8192 + bb * 2048 + scolx;

#define STAGE(bufp, kv0)                                              \
  do {                                                                \
    gload_lds16(kg + (size_t)(kv0) * 1024, &Ks[bufp][wid * 8 * 64]);  \
    gload_lds16(vg + (kv0), &Vs[bufp][wid * 8 * 64]);                 \
  } while (0)

  auto TILE = [&](int t, int buf) {
    const int kv0 = t * 64;
    const bf16_t* KsB = &Ks[buf][0];
    const bf16_t* VsB = &Vs[buf][0];

    // QK^T swapped: s[n] row = kv (n*16 + lg*4 + r), col = q (= l15)
    f32x4 s[4];
#pragma unroll
    for (int n = 0; n < 4; n++) s[n] = f32x4{0.f, 0.f, 0.f, 0.f};
    __builtin_amdgcn_s_setprio(1);
#pragma unroll
    for (int ks = 0; ks < 2; ks++) {
      bf16x8 qf = ks ? qf1 : qf0;
      const int c2 = ks * 64 + lg * 16;
#pragma unroll
      for (int n = 0; n < 4; n++) {
        bf16x8 kf = lds_frag(KsB, n * 16 + l15, c2);
        s[n] = MFMA_BF16(kf, qf, s[n], 0, 0, 0);
      }
    }
    __builtin_amdgcn_s_setprio(0);

    // logits (base-2, pre-scaled bias)
    float lg2[4][4];
    const bool farp = (q0 - kv0) >= 192;   // min rel = q0-kv0-63 >= 129
    const bool farn = (kv0 - q0) >= 256;   // max rel = q0+127-kv0 <= -129
    if (farp || farn) {
      const float cb = farp ? cbp : cbn;
#pragma unroll
      for (int n = 0; n < 4; n++)
#pragma unroll
        for (int r = 0; r < 4; r++) lg2[n][r] = s[n][r] * SCL + cb;
    } else {
#pragma unroll
      for (int n = 0; n < 4; n++) {
        const float* btn = bt + (rq - kv0 - n * 16 - lg * 4);
#pragma unroll
        for (int r = 0; r < 4; r++) lg2[n][r] = s[n][r] * SCL + btn[-r];
      }
    }

    // row max: 15 in-lane + 2 shuffles
    float tmax = lg2[0][0];
#pragma unroll
    for (int n = 0; n < 4; n++)
#pragma unroll
      for (int r = 0; r < 4; r++) tmax = fmaxf(tmax, lg2[n][r]);
    tmax = fmaxf(tmax, __shfl_xor(tmax, 16, 64));
    tmax = fmaxf(tmax, __shfl_xor(tmax, 32, 64));

    // defer-max (T13, THR=8)
    if (!__all(tmax - mrow <= 8.0f)) {
      float mnew = fmaxf(mrow, tmax);
      float rs = exp2f(mrow - mnew);
      mrow = mnew;
      lrow *= rs;
      float rr0 = __shfl(rs, (lg << 2) + 0, 64);
      float rr1 = __shfl(rs, (lg << 2) + 1, 64);
      float rr2 = __shfl(rs, (lg << 2) + 2, 64);
      float rr3 = __shfl(rs, (lg << 2) + 3, 64);
#pragma unroll
      for (int dn = 0; dn < 4; dn++) {
        f32x4 a = acc[dn];
        a[0] *= rr0; a[1] *= rr1; a[2] *= rr2; a[3] *= rr3;
        acc[dn] = a;
      }
    }

    // P = exp2(lg2 - m); pack pairs, store to word-permuted Ps
    float psum = 0.f;
#pragma unroll
    for (int n = 0; n < 4; n++) {
      float p0 = exp2f(lg2[n][0] - mrow);
      float p1 = exp2f(lg2[n][1] - mrow);
      float p2 = exp2f(lg2[n][2] - mrow);
      float p3 = exp2f(lg2[n][3] - mrow);
      psum += (p0 + p1) + (p2 + p3);
      unsigned w0, w1;
      asm("v_cvt_pk_bf16_f32 %0, %1, %2" : "=v"(w0) : "v"(p0), "v"(p1));
      asm("v_cvt_pk_bf16_f32 %0, %1, %2" : "=v"(w1) : "v"(p2), "v"(p3));
      uint2 wv = {w0, w1};
      *(uint2*)(pw + (((l15 << 7) + n * 32 + (lg >> 1) * 16 + (lg & 1) * 8)
                      ^ ((l15 & 7) << 4))) = wv;
    }
    psum += __shfl_xor(psum, 16, 64);
    psum += __shfl_xor(psum, 32, 64);
    lrow += psum;

    asm volatile("s_waitcnt lgkmcnt(0)" ::: "memory");
    __builtin_amdgcn_sched_barrier(0);

    // PV: A = P (row=q=l15, k = ks*32+lg*8+e), B = Vt rows d
    __builtin_amdgcn_s_setprio(1);
#pragma unroll
    for (int ks = 0; ks < 2; ks++) {
      const int c2 = ks * 64 + lg * 16;
      bf16x8 pa = *(const bf16x8*)(pw + (((l15 << 7) + ks * 64 + (lg >> 1) * 32 + (lg & 1) * 16)
                                         ^ ((l15 & 7) << 4)));
#pragma unroll
      for (int dn = 0; dn < 4; dn++) {
        bf16x8 vf = lds_frag(VsB, dn * 16 + l15, c2);
        acc[dn] = MFMA_BF16(pa, vf, acc[dn], 0, 0, 0);
      }
    }
    __builtin_amdgcn_s_setprio(0);
  };

  // prologue: 2 tiles in flight
  STAGE(0, 0);
  STAGE(1, 64);

  int cur = 0, nx2 = 2;                     // buf(t), buf(t+2)
  for (int t = 0; t < 31; t++) {
    asm volatile("s_waitcnt vmcnt(2)" ::: "memory");   // tile t's loads landed
    __syncthreads();
    TILE(t, cur);
    if (t < 30) STAGE(nx2, (t + 2) * 64);
    cur = (cur == 2) ? 0 : cur + 1;
    nx2 = (nx2 == 2) ? 0 : nx2 + 1;
  }
  asm volatile("s_waitcnt vmcnt(0)" ::: "memory");
  __syncthreads();
  TILE(31, cur);
#undef STAGE

  // epilogue: acc row = q-index lg*4+r, col = d = dn*16 + l15
  float li0 = __shfl(lrow, (lg << 2) + 0, 64);
  float li1 = __shfl(lrow, (lg << 2) + 1, 64);
  float li2 = __shfl(lrow, (lg << 2) + 2, 64);
  float li3 = __shfl(lrow, (lg << 2) + 3, 64);
  float inv[4] = {1.f / li0, 1.f / li1, 1.f / li2, 1.f / li3};
  const int qr0 = q0 + wid * 16 + (lg << 2);
#pragma unroll
  for (int dn = 0; dn < 4; dn++)
#pragma unroll
    for (int r = 0; r < 4; r++)
      ctx[cbase + (size_t)(qr0 + r) * 512 + hc + dn * 16 + l15] = (bf16_t)(acc[dn][r] * inv[r]);
}

// ---------------- residual + LayerNorm ----------------
__global__ __launch_bounds__(256) void lnres_k(const float* __restrict__ a,
                                               const float* __restrict__ bsrc,
                                               const float* __restrict__ sc,
                                               const float* __restrict__ bi,
                                               float* __restrict__ outf,
                                               bf16_t* __restrict__ outb) {
  int row = blockIdx.x * 4 + (threadIdx.x >> 6);
  int lane = threadIdx.x & 63;
  size_t base = (size_t)row * 512 + lane * 8;
  float4 a0 = *(const float4*)(a + base), a1 = *(const float4*)(a + base + 4);
  float4 b0 = *(const float4*)(bsrc + base), b1 = *(const float4*)(bsrc + base + 4);
  float v[8] = {a0.x + b0.x, a0.y + b0.y, a0.z + b0.z, a0.w + b0.w,
                a1.x + b1.x, a1.y + b1.y, a1.z + b1.z, a1.w + b1.w};
  float s1 = 0.f, s2 = 0.f;
#pragma unroll
  for (int j = 0; j < 8; j++) { s1 += v[j]; s2 += v[j] * v[j]; }
#pragma unroll
  for (int off = 1; off < 64; off <<= 1) {
    s1 += __shfl_xor(s1, off, 64);
    s2 += __shfl_xor(s2, off, 64);
  }
  float mu = s1 * (1.f / 512.f);
  float var = s2 * (1.f / 512.f) - mu * mu;
  float rstd = rsqrtf(var + 1e-6f);
  int c = lane * 8;
  float4 sc0 = *(const float4*)(sc + c), sc1 = *(const float4*)(sc + c + 4);
  float4 bi0 = *(const float4*)(bi + c), bi1 = *(const float4*)(bi + c + 4);
  float scv[8] = {sc0.x, sc0.y, sc0.z, sc0.w, sc1.x, sc1.y, sc1.z, sc1.w};
  float biv[8] = {bi0.x, bi0.y, bi0.z, bi0.w, bi1.x, bi1.y, bi1.z, bi1.w};
  float o[8];
#pragma unroll
  for (int j = 0; j < 8; j++) o[j] = (v[j] - mu) * rstd * scv[j] + biv[j];
  *(float4*)(outf + base) = make_float4(o[0], o[1], o[2], o[3]);
  *(float4*)(outf + base + 4) = make_float4(o[4], o[5], o[6], o[7]);
  if (outb) {
    bf16x8 ob = {(bf16_t)o[0], (bf16_t)o[1], (bf16_t)o[2], (bf16_t)o[3],
                 (bf16_t)o[4], (bf16_t)o[5], (bf16_t)o[6], (bf16_t)o[7]};
    *(bf16x8*)(outb + base) = ob;
  }
}

// ---------------- host launcher ----------------
extern "C" void kernel_launch(void* const* d_in, const int* in_sizes, int n_in,
                              void* d_out, int out_size, void* d_ws, size_t ws_size,
                              hipStream_t stream) {
  const float* x    = (const float*)d_in[0];
  const float* Wq   = (const float*)d_in[1];
  const float* bq   = (const float*)d_in[2];
  const float* Wk   = (const float*)d_in[3];
  const float* bk   = (const float*)d_in[4];
  const float* Wv   = (const float*)d_in[5];
  const float* bv   = (const float*)d_in[6];
  const float* Wo   = (const float*)d_in[7];
  const float* bo   = (const float*)d_in[8];
  const float* relb = (const float*)d_in[9];
  const float* W1   = (const float*)d_in[10];
  const float* b1   = (const float*)d_in[11];
  const float* W2   = (const float*)d_in[12];
  const float* b2   = (const float*)d_in[13];
  const float* ln1s = (const float*)d_in[14];
  const float* ln1b = (const float*)d_in[15];
  const float* ln2s = (const float*)d_in[16];
  const float* ln2b = (const float*)d_in[17];

  char* w = (char*)d_ws;
  bf16_t* xb    = (bf16_t*)(w + 0);          //  8 MB [8192][512]
  bf16_t* qk    = (bf16_t*)(w + 8388608);    // 16 MB [8192][1024]
  bf16_t* vtg   = (bf16_t*)(w + 25165824);   //  8 MB [512][8192]
  bf16_t* ctxb  = (bf16_t*)(w + 33554432);   //  8 MB
  float*  tmpf2 = (float*)(w + 33554432);    // 16 MB (FFN2 out; overlays dead ctxb)
  bf16_t* x1b   = (bf16_t*)(w + 50331648);   //  8 MB
  bf16_t* WqkT  = (bf16_t*)(w + 58720256);   //  1 MB [1024][512]
  bf16_t* WvT   = (bf16_t*)(w + 59768832);   // 0.5 MB
  bf16_t* WoT   = (bf16_t*)(w + 60293120);   // 0.5 MB
  bf16_t* W1T   = (bf16_t*)(w + 60817408);   //  2 MB [2048][512]
  bf16_t* W2T   = (bf16_t*)(w + 62914560);   //  2 MB [512][2048]
  float*  btab  = (float*)(w + 65011712);    // 128 KB
  float*  bqk   = (float*)(w + 65273856);    //  4 KB
  float*  x1f   = (float*)(w + 65798144);    // 16 MB
  float*  tmpf  = (float*)(w + 82575360);    // 16 MB (Wo out)
  bf16_t* ffh   = (bf16_t*)(w + 0);          // 32 MB [8192][2048]; overlays xb+qk+vtg

  cvt_k<<<4096, 256, 0, stream>>>(x, xb, 8192 * 512 / 4);
  cvtT_k<<<dim3(8, 8), 256, 0, stream>>>(Wq, WqkT, 512, 512);
  cvtT_k<<<dim3(8, 8), 256, 0, stream>>>(Wk, WqkT + 512 * 512, 512, 512);
  cvtT_k<<<dim3(8, 8), 256, 0, stream>>>(Wv, WvT, 512, 512);
  cvtT_k<<<dim3(8, 8), 256, 0, stream>>>(Wo, WoT, 512, 512);
  cvtT_k<<<dim3(32, 8), 256, 0, stream>>>(W1, W1T, 512, 2048);
  cvtT_k<<<dim3(8, 32), 256, 0, stream>>>(W2, W2T, 2048, 512);
  relbias_k<<<128, 256, 0, stream>>>(relb, btab);
  cat2_k<<<4, 256, 0, stream>>>(bq, bk, bqk);

  // QK projection [8192][1024]
  gemm_k<128, 128, 2, 2, 0, 0, 0><<<dim3(64, 8), 256, 0, stream>>>(xb, WqkT, bqk, qk, 8192, 1024, 512);
  // V^T projection: Vt[dout][seq] = WvT @ xb^T  (row bias bv), 64x128 tiles
  gemm_k<64, 128, 1, 4, 0, 0, 1><<<dim3(8, 64), 256, 0, stream>>>(WvT, xb, bv, vtg, 512, 8192, 512);

  // attention: 8 waves, QBLK=128
  attn_k<<<dim3(16, 32), 512, 0, stream>>>(qk, qk + 512, vtg, btab, relb, ctxb);

  // Wo + residual LN1
  gemm_k<64, 128, 1, 4, 1, 0, 0><<<dim3(128, 4), 256, 0, stream>>>(ctxb, WoT, bo, tmpf, 8192, 512, 512);
  lnres_k<<<2048, 256, 0, stream>>>(x, tmpf, ln1s, ln1b, x1f, x1b);

  // FFN
  gemm_k<128, 128, 2, 2, 0, 1, 0><<<dim3(64, 16), 256, 0, stream>>>(x1b, W1T, b1, ffh, 8192, 2048, 512);
  gemm_k<64, 128, 1, 4, 1, 0, 0><<<dim3(128, 4), 256, 0, stream>>>(ffh, W2T, b2, tmpf2, 8192, 512, 2048);
  lnres_k<<<2048, 256, 0, stream>>>(x1f, tmpf2, ln2s, ln2b, (float*)d_out, (bf16_t*)nullptr);
}